// Round 1
// baseline (1291.451 us; speedup 1.0000x reference)
//
#include <hip/hip_runtime.h>

#define VOCAB    1825324
#define NBW      57042     // ceil(VOCAB/32)
#define NBW_PAD  57344
#define BSZ      4096
#define DIM      128
#define SEQ      20
#define NNEG     16384
#define UU       20480     // BSZ + NNEG

typedef __attribute__((ext_vector_type(8))) short bf16x8;
typedef __attribute__((ext_vector_type(4))) short s16x4;
typedef __attribute__((ext_vector_type(4))) float f32x4;

__device__ __forceinline__ short f2bf(float f) {
    // round-to-nearest-even f32 -> bf16 (inputs are finite/normal here)
    unsigned u = __float_as_uint(f);
    unsigned r = (u + 0x7fffu + ((u >> 16) & 1u)) >> 16;
    return (short)r;
}

// K1: zero the vocab bitmask + the tail of d_out (second output: zeros)
__global__ void k1_zero(unsigned* __restrict__ maskb, float* __restrict__ outTail, int tailN) {
    int i = blockIdx.x * 256 + threadIdx.x;
    if (i < NBW_PAD) maskb[i] = 0u;
    int j = i - NBW_PAD;
    if (j >= 0 && j < tailN) outTail[j] = 0.0f;
}

// K2: scatter membership bits for the 20480 union labels
__global__ void k2_scatter(const int* __restrict__ labels, const int* __restrict__ uni_neg,
                           unsigned* __restrict__ maskb) {
    int i = blockIdx.x * 256 + threadIdx.x;
    if (i >= UU) return;
    int v = (i < BSZ) ? labels[i] : uni_neg[i - BSZ];
    atomicOr(&maskb[v >> 5], 1u << (v & 31));
}

// K3: word-granular exclusive popcount prefix over the bitmask (single block)
__global__ void k3_prefix(const unsigned* __restrict__ maskb, unsigned* __restrict__ wpre) {
    __shared__ unsigned sums[1024];
    const int PER = 56;                 // 56*1024 = 57344 >= NBW
    int t = threadIdx.x;
    int start = t * PER;
    int end = start + PER; if (end > NBW) end = NBW;
    unsigned s = 0;
    for (int w = start; w < end; ++w) s += __popc(maskb[w]);
    sums[t] = s;
    __syncthreads();
    for (int off = 1; off < 1024; off <<= 1) {
        unsigned v = (t >= off) ? sums[t - off] : 0u;
        __syncthreads();
        sums[t] += v;
        __syncthreads();
    }
    unsigned run = sums[t] - s;         // exclusive prefix for this thread's range
    for (int w = start; w < end; ++w) { wpre[w] = run; run += __popc(maskb[w]); }
}

// K4: rank each union label; scatter bf16 embedding row, log-prob correction, pos_idx
__global__ void k4_rank(const int* __restrict__ labels, const int* __restrict__ uni_neg,
                        const float* __restrict__ probs, const float* __restrict__ emb,
                        const unsigned* __restrict__ maskb, const unsigned* __restrict__ wpre,
                        const float* __restrict__ icf,
                        int* __restrict__ posIdx, float* __restrict__ corr,
                        short* __restrict__ embS) {
    int i = blockIdx.x * 2 + (threadIdx.x >> 7);   // label index [0, 20480)
    int k = threadIdx.x & 127;
    int v = (i < BSZ) ? labels[i] : uni_neg[i - BSZ];
    int w = v >> 5, b = v & 31;
    unsigned mw = maskb[w];
    int r = (int)wpre[w] + __popc(mw & ((1u << b) - 1u));   // rank = sorted position
    if (k == 0) {
        corr[r] = icf[0] * logf(probs[v] + 1e-11f);
        if (i < BSZ) posIdx[i] = r;
    }
    embS[(size_t)r * DIM + k] = f2bf(emb[(size_t)v * DIM + k]);
}

// K4b: cast x to bf16
__global__ void k_xcast(const float* __restrict__ x, short* __restrict__ xb) {
    int i = blockIdx.x * 256 + threadIdx.x;
    if (i * 4 >= BSZ * DIM) return;
    f32x4 v = *(const f32x4*)(x + (size_t)i * 4);
    s16x4 o;
    o[0] = f2bf(v[0]); o[1] = f2bf(v[1]); o[2] = f2bf(v[2]); o[3] = f2bf(v[3]);
    *(s16x4*)(xb + (size_t)i * 4) = o;
}

// K5: bf16 MFMA GEMM (4096x20480, K=128) with fused correction, temperature,
// and positive-column permutation in the store address.
__global__ __launch_bounds__(256) void k5_gemm(
    const short* __restrict__ xb, const short* __restrict__ embS,
    const float* __restrict__ corr, const int* __restrict__ posIdx,
    const float* __restrict__ tempPtr, float* __restrict__ out) {
    __shared__ short Bt[128][136];   // +8 pad -> 2-way bank aliasing (free)
    __shared__ float corrS[128];
    __shared__ int   posS[128];

    const int t = threadIdx.x;
    const int lane = t & 63;
    const int wave = t >> 6;
    const int by = blockIdx.x;      // row tile [0,32)
    const int bx = blockIdx.y;      // col tile [0,160)

    // stage B^T tile: 128 cols x 128 k, bf16
    {
        const int q = t & 15;       // 8-elem chunk within row
        const int c0 = t >> 4;
        #pragma unroll
        for (int j = 0; j < 8; ++j) {
            int c = j * 16 + c0;
            bf16x8 v = *(const bf16x8*)(embS + (size_t)(bx * 128 + c) * DIM + q * 8);
            *(bf16x8*)&Bt[c][q * 8] = v;
        }
    }
    if (t < 128) {
        corrS[t] = corr[bx * 128 + t];
        posS[t]  = posIdx[by * 128 + t];
    }

    // A fragments straight from global (x is tiny and cache-resident)
    const int kk = (lane >> 4) << 3;             // 0,8,16,24
    const int m0 = by * 128 + wave * 32 + (lane & 15);
    bf16x8 afrag[2][4];
    #pragma unroll
    for (int rt = 0; rt < 2; ++rt)
        #pragma unroll
        for (int ks = 0; ks < 4; ++ks)
            afrag[rt][ks] = *(const bf16x8*)(xb + (size_t)(m0 + rt * 16) * DIM + ks * 32 + kk);

    f32x4 acc[8][2];
    const f32x4 zero = {0.f, 0.f, 0.f, 0.f};
    #pragma unroll
    for (int ct = 0; ct < 8; ++ct) { acc[ct][0] = zero; acc[ct][1] = zero; }

    __syncthreads();

    #pragma unroll
    for (int ct = 0; ct < 8; ++ct) {
        const int cc = ct * 16 + (lane & 15);
        #pragma unroll
        for (int ks = 0; ks < 4; ++ks) {
            bf16x8 bfrag = *(const bf16x8*)&Bt[cc][ks * 32 + kk];
            acc[ct][0] = __builtin_amdgcn_mfma_f32_16x16x32_bf16(afrag[0][ks], bfrag, acc[ct][0], 0, 0, 0);
            acc[ct][1] = __builtin_amdgcn_mfma_f32_16x16x32_bf16(afrag[1][ks], bfrag, acc[ct][1], 0, 0, 0);
        }
    }

    // epilogue: val = (acc - corr[c]) / temp; store with positive-col permutation
    const float invT = 1.0f / tempPtr[0];
    const int rq = (lane >> 4) << 2;
    #pragma unroll
    for (int ct = 0; ct < 8; ++ct) {
        const int c = bx * 128 + ct * 16 + (lane & 15);
        const float crT = corrS[ct * 16 + (lane & 15)] * invT;
        #pragma unroll
        for (int rt = 0; rt < 2; ++rt) {
            #pragma unroll
            for (int i = 0; i < 4; ++i) {
                const int rl = wave * 32 + rt * 16 + rq + i;
                const int p = posS[rl];
                const float val = acc[ct][rt][i] * invT - crT;
                const int ocol = (c == p) ? 0 : ((c < p) ? c + 1 : c);
                out[(size_t)(by * 128 + rl) * UU + ocol] = val;
            }
        }
    }
}

// K6: zero the masked (seen-item) entries — at most 81920 probes, ~1k actual hits
__global__ void k6_fixup(const int* __restrict__ item_seq, const unsigned* __restrict__ maskb,
                         const unsigned* __restrict__ wpre, const int* __restrict__ posIdx,
                         float* __restrict__ out) {
    int i = blockIdx.x * 256 + threadIdx.x;
    if (i >= BSZ * SEQ) return;
    int row = i / SEQ;
    int v = item_seq[i];
    unsigned mw = maskb[v >> 5];
    if (!((mw >> (v & 31)) & 1u)) return;          // not in union set
    int r = (int)wpre[v >> 5] + __popc(mw & ((1u << (v & 31)) - 1u));
    int p = posIdx[row];
    if (r == p) return;                            // positive never masked
    int ocol = (r < p) ? r + 1 : r;
    out[(size_t)row * UU + ocol] = 0.0f;
}

extern "C" void kernel_launch(void* const* d_in, const int* in_sizes, int n_in,
                              void* d_out, int out_size, void* d_ws, size_t ws_size,
                              hipStream_t stream) {
    const float* x        = (const float*)d_in[0];
    const int*   labels   = (const int*)  d_in[1];
    const int*   item_seq = (const int*)  d_in[2];
    const float* probs    = (const float*)d_in[3];
    const int*   uni_neg  = (const int*)  d_in[4];
    const float* emb      = (const float*)d_in[5];
    const float* temp     = (const float*)d_in[6];
    const float* icf      = (const float*)d_in[7];
    float* out = (float*)d_out;

    char* ws = (char*)d_ws;
    unsigned* maskb = (unsigned*)(ws);            // 57344 * 4 = 229376
    unsigned* wpre  = (unsigned*)(ws + 229376);   // 57344 * 4
    int*   posIdx   = (int*)    (ws + 458752);    // 4096 * 4
    float* corr     = (float*)  (ws + 475136);    // 20480 * 4
    short* xb       = (short*)  (ws + 557056);    // 4096*128*2
    short* embS     = (short*)  (ws + 1605632);   // 20480*128*2  (total ~6.8 MB)

    int tailN = out_size - BSZ * UU; if (tailN < 0) tailN = 0;
    int n1 = NBW_PAD + tailN;
    k1_zero<<<(n1 + 255) / 256, 256, 0, stream>>>(maskb, out + (size_t)BSZ * UU, tailN);
    k2_scatter<<<(UU + 255) / 256, 256, 0, stream>>>(labels, uni_neg, maskb);
    k3_prefix<<<1, 1024, 0, stream>>>(maskb, wpre);
    k4_rank<<<UU / 2, 256, 0, stream>>>(labels, uni_neg, probs, emb, maskb, wpre, icf,
                                        posIdx, corr, embS);
    k_xcast<<<(BSZ * DIM / 4 + 255) / 256, 256, 0, stream>>>(x, xb);
    dim3 g5(32, 160);   // x = row tiles (consecutive blocks share the B col-tile's L2 set)
    k5_gemm<<<g5, 256, 0, stream>>>(xb, embS, corr, posIdx, temp, out);
    k6_fixup<<<(BSZ * SEQ + 255) / 256, 256, 0, stream>>>(item_seq, maskb, wpre, posIdx, out);
}